// Round 8
// baseline (132.585 us; speedup 1.0000x reference)
//
#include <hip/hip_runtime.h>
#include <stdint.h>

// Problem constants (fixed-shape problem)
#define NN 10000   // nodes
#define NB 8       // batch
#define NP 12      // periods
#define NT 64      // T
#define NC 32      // C
#define KFP 96     // NF*NP
#define BCAP 96    // bucket capacity per node (max in-degree ~38 for E=160k uniform)
#define FCN 100    // nodes per k_final chunk
#define FCH 100    // chunks (100*100 == NN)
#define XB 3750    // transform blocks (3750*256 = 960000 ushort8 slots)
// x  layout: [b][n][f][p] -> idx = b*960000 + n*96 + k, k = f*12+p
// xh layout: [n][b][k] bf16 -> row of 1536 BYTES per node
// h1t layout: [n][96]  (r = b*12+p)

__device__ __forceinline__ float bf_lo(unsigned u) { return __uint_as_float(u << 16); }
__device__ __forceinline__ float bf_hi(unsigned u) { return __uint_as_float(u & 0xffff0000u); }
__device__ __forceinline__ unsigned short f2bf(float f) {
    unsigned u = __float_as_uint(f);
    return (unsigned short)((u + 0x7fffu + ((u >> 16) & 1u)) >> 16);
}

// ---------------- xf: x -> bf16 transpose ----------------
__global__ __launch_bounds__(256) void k_xf(const float* __restrict__ x,
                                            unsigned short* __restrict__ xh) {
    // bf16 transform: slot s = (n*8+b)*12 + q ; write 8 values at xh[s*8]
    const int s = blockIdx.x * 256 + threadIdx.x;
    const int n = s / 96, r = s - n * 96;
    const int b = r / 12, q = r - b * 12;
    const float* px = x + (size_t)b * 960000 + n * 96 + q * 8;
    const float4 f0 = *(const float4*)px;
    const float4 f1 = *(const float4*)(px + 4);
    unsigned u0 = (unsigned)f2bf(f0.x) | ((unsigned)f2bf(f0.y) << 16);
    unsigned u1 = (unsigned)f2bf(f0.z) | ((unsigned)f2bf(f0.w) << 16);
    unsigned u2 = (unsigned)f2bf(f1.x) | ((unsigned)f2bf(f1.y) << 16);
    unsigned u3 = (unsigned)f2bf(f1.z) | ((unsigned)f2bf(f1.w) << 16);
    *(uint4*)(xh + (size_t)s * 8) = make_uint4(u0, u1, u2, u3);
}

// ---------------- edge: bucket scatter + weighted degree ----------------
__global__ __launch_bounds__(256) void k_edge(const int* __restrict__ rowp, const int* __restrict__ colp,
                                              const float* __restrict__ ew,
                                              float* __restrict__ deg, int* __restrict__ count,
                                              uint2* __restrict__ bucket, int E) {
    const int e = blockIdx.x * 256 + threadIdx.x;
    if (e < E) {
        const int c = colp[e];
        const float w = ew[e];
        atomicAdd(&deg[c], w);
        const int slot = atomicAdd(&count[c], 1);
        if (slot < BCAP) bucket[c * BCAP + slot] = make_uint2((unsigned)rowp[e], __float_as_uint(w));
    }
}

// ---------------- misc: small matrices (block 0) | out = lin2 bias (block 1) ----------------
// sm layout (floats): [0..11] probs, [16..271] Mz[f*32+c], [272..527] Mh, [528..559] cz, [560..591] ch
__global__ __launch_bounds__(256) void k_misc(
    const float* __restrict__ Wz, const float* __restrict__ bz,
    const float* __restrict__ Wh, const float* __restrict__ bh,
    const float* __restrict__ Lzw, const float* __restrict__ Lzb,
    const float* __restrict__ Lhw, const float* __restrict__ Lhb,
    const float* __restrict__ att, const float* __restrict__ l2b,
    float* __restrict__ sm, float* __restrict__ out) {
    const int tid = threadIdx.x;
    if (blockIdx.x == 0) {
        const int t = tid, f = t >> 5, c = t & 31;
        float mz = 0.f, mh = 0.f;
        for (int j = 0; j < NC; ++j) {
            mz += Wz[f * NC + j] * Lzw[j * NC + c];
            mh += Wh[f * NC + j] * Lhw[j * NC + c];
        }
        sm[16 + t]  = mz;
        sm[272 + t] = mh;
        if (t < NC) {
            float cz = Lzb[t], ch = Lhb[t];
            for (int j = 0; j < NC; ++j) {
                cz += bz[j] * Lzw[j * NC + t];
                ch += bh[j] * Lhw[j * NC + t];
            }
            sm[528 + t] = cz;
            sm[560 + t] = ch;
        }
        if (t == 0) {
            float m = -1e30f;
            for (int p = 0; p < NP; ++p) m = fmaxf(m, att[p]);
            float e[NP]; float s = 0.f;
            for (int p = 0; p < NP; ++p) { e[p] = __expf(att[p] - m); s += e[p]; }
            for (int p = 0; p < NP; ++p) sm[p] = e[p] / s;
        }
    } else {
        // out init with lin2 bias: out[b*768 + t*12 + p] = l2b[t]
        for (int idx = tid; idx < NB * NT * NP; idx += 256) {
            const int t = (idx / 12) & 63;
            out[idx] = l2b[t];
        }
    }
}

#define ACC3(U0, U1, U2, W)                                                     \
    a[0] = fmaf(bf_lo(U0.x), W, a[0]); a[1]  = fmaf(bf_hi(U0.x), W, a[1]);      \
    a[2] = fmaf(bf_lo(U0.y), W, a[2]); a[3]  = fmaf(bf_hi(U0.y), W, a[3]);      \
    a[4] = fmaf(bf_lo(U1.x), W, a[4]); a[5]  = fmaf(bf_hi(U1.x), W, a[5]);      \
    a[6] = fmaf(bf_lo(U1.y), W, a[6]); a[7]  = fmaf(bf_hi(U1.y), W, a[7]);      \
    a[8] = fmaf(bf_lo(U2.x), W, a[8]); a[9]  = fmaf(bf_hi(U2.x), W, a[9]);      \
    a[10] = fmaf(bf_lo(U2.y), W, a[10]); a[11] = fmaf(bf_hi(U2.y), W, a[11])

// ---------------- main: wave-per-node gather (4-deep pipelined) + GRU + lin1 ----------------
__global__ __launch_bounds__(256) void k_main(
    const unsigned short* __restrict__ xh, const float* __restrict__ deg,
    const int* __restrict__ count, const uint2* __restrict__ bucket,
    const float* __restrict__ sm,
    const float* __restrict__ l1w, const float* __restrict__ l1b,
    float* __restrict__ h1t) {
    __shared__ float2 sMzh[256];       // (Mz,Mh)[f*32+c]
    __shared__ float2 sczh[32];
    __shared__ float  sprobs[12], sl1b[12];
    __shared__ float  sl1w[384];
    __shared__ float  sY[4][800];      // per-wave [b*100 + k], 16B-aligned rows
    __shared__ float  sHA[4][264];     // per-wave [b*33 + c]  (padded)
    __shared__ uint2  sE[4][64];       // per-wave edge strip

    const int tid = threadIdx.x;
    const int wv = tid >> 6, l = tid & 63;
    const int n = blockIdx.x * 4 + wv;

    sMzh[tid] = make_float2(sm[16 + tid], sm[272 + tid]);
    if (tid < 32) sczh[tid] = make_float2(sm[528 + tid], sm[560 + tid]);
    if (tid < 12) { sprobs[tid] = sm[tid]; sl1b[tid] = l1b[tid]; }
    for (int i = tid; i < 384; i += 256) sl1w[i] = l1w[i];
    __syncthreads();   // weights visible to all waves; ONLY barrier in the kernel

    // ---- wave-private gather: lane owns 24 bytes (12 bf16) of its node's 1536-byte row ----
    const char* xbase = (const char*)xh;
    const unsigned loff = (unsigned)l * 24u;
    const float dn = rsqrtf(deg[n] + 1.0f);   // dis[n]; deg excludes self-loop
    float a[12];
    {
        const float sn = dn * dn;   // self-loop norm
        const char* p0 = xbase + ((unsigned)n * 1536u + loff);
        const uint2 u0 = *(const uint2*)p0;
        const uint2 u1 = *(const uint2*)(p0 + 8);
        const uint2 u2 = *(const uint2*)(p0 + 16);
        a[0] = bf_lo(u0.x) * sn; a[1]  = bf_hi(u0.x) * sn;
        a[2] = bf_lo(u0.y) * sn; a[3]  = bf_hi(u0.y) * sn;
        a[4] = bf_lo(u1.x) * sn; a[5]  = bf_hi(u1.x) * sn;
        a[6] = bf_lo(u1.y) * sn; a[7]  = bf_hi(u1.y) * sn;
        a[8] = bf_lo(u2.x) * sn; a[9]  = bf_hi(u2.x) * sn;
        a[10] = bf_lo(u2.y) * sn; a[11] = bf_hi(u2.y) * sn;
    }
    const int cnt = min(count[n], BCAP);
    const uint2* bk = bucket + n * BCAP;
    uint2* sEw = &sE[wv][0];
    for (int base = 0; base < cnt; base += 64) {
        const int m_ = min(64, cnt - base);
        const int m4 = (m_ + 3) & ~3;
        {   // stage with zero-weight padding to multiple of 4 (wave-synchronous)
            uint2 ent = make_uint2(0u, 0u);
            if (l < m_) {
                const uint2 e = bk[base + l];
                const float w = __uint_as_float(e.y);
                const float nrm = rsqrtf(deg[e.x] + 1.0f) * w * dn;
                ent = make_uint2(e.x * 1536u, __float_as_uint(nrm));
            }
            if (l < m4) sEw[l] = ent;
        }
        for (int q = 0; q < m4; q += 4) {   // 4-deep: 12 loads in flight before FMAs
            const uint2 e0 = sEw[q + 0], e1 = sEw[q + 1], e2 = sEw[q + 2], e3 = sEw[q + 3];
            const char* pA = xbase + (e0.x + loff);
            const char* pB = xbase + (e1.x + loff);
            const char* pC = xbase + (e2.x + loff);
            const char* pD = xbase + (e3.x + loff);
            const uint2 A0 = *(const uint2*)pA, A1 = *(const uint2*)(pA + 8), A2 = *(const uint2*)(pA + 16);
            const uint2 B0 = *(const uint2*)pB, B1 = *(const uint2*)(pB + 8), B2 = *(const uint2*)(pB + 16);
            const uint2 C0 = *(const uint2*)pC, C1 = *(const uint2*)(pC + 8), C2 = *(const uint2*)(pC + 16);
            const uint2 D0 = *(const uint2*)pD, D1 = *(const uint2*)(pD + 8), D2 = *(const uint2*)(pD + 16);
            const float w0 = __uint_as_float(e0.y), w1 = __uint_as_float(e1.y);
            const float w2 = __uint_as_float(e2.y), w3 = __uint_as_float(e3.y);
            ACC3(A0, A1, A2, w0);
            ACC3(B0, B1, B2, w1);
            ACC3(C0, C1, C2, w2);
            ACC3(D0, D1, D2, w3);
        }
    }
    {   // lane holds (b=l>>3, f=l&7, all 12 p): 3x float4 write
        float* yp = &sY[wv][(l >> 3) * 100 + (l & 7) * 12];
        *(float4*)yp       = make_float4(a[0], a[1], a[2], a[3]);
        *(float4*)(yp + 4) = make_float4(a[4], a[5], a[6], a[7]);
        *(float4*)(yp + 8) = make_float4(a[8], a[9], a[10], a[11]);
    }

    // ---- GRU-collapse (wave-private): lane does 4 tasks (b = 2*t4 + (l>=32), c = l&31) ----
    const int c = l & 31;
    float2 m8[8];
    #pragma unroll
    for (int f = 0; f < 8; ++f) m8[f] = sMzh[f * 32 + c];
    const float2 czh = sczh[c];
    float pr[12];
    #pragma unroll
    for (int p = 0; p < 12; ++p) pr[p] = sprobs[p];

    #pragma unroll
    for (int t4 = 0; t4 < 4; ++t4) {
        const int b = t4 * 2 + (l >> 5);
        const float* yb = &sY[wv][b * 100];
        float szv[12], shv[12];
        #pragma unroll
        for (int p = 0; p < 12; ++p) { szv[p] = czh.x; shv[p] = czh.y; }
        #pragma unroll
        for (int f = 0; f < 8; ++f) {
            const float4 y0 = *(const float4*)(yb + f * 12);
            const float4 y1 = *(const float4*)(yb + f * 12 + 4);
            const float4 y2 = *(const float4*)(yb + f * 12 + 8);
            const float mz = m8[f].x, mh = m8[f].y;
            szv[0] = fmaf(y0.x, mz, szv[0]); shv[0] = fmaf(y0.x, mh, shv[0]);
            szv[1] = fmaf(y0.y, mz, szv[1]); shv[1] = fmaf(y0.y, mh, shv[1]);
            szv[2] = fmaf(y0.z, mz, szv[2]); shv[2] = fmaf(y0.z, mh, shv[2]);
            szv[3] = fmaf(y0.w, mz, szv[3]); shv[3] = fmaf(y0.w, mh, shv[3]);
            szv[4] = fmaf(y1.x, mz, szv[4]); shv[4] = fmaf(y1.x, mh, shv[4]);
            szv[5] = fmaf(y1.y, mz, szv[5]); shv[5] = fmaf(y1.y, mh, shv[5]);
            szv[6] = fmaf(y1.z, mz, szv[6]); shv[6] = fmaf(y1.z, mh, shv[6]);
            szv[7] = fmaf(y1.w, mz, szv[7]); shv[7] = fmaf(y1.w, mh, shv[7]);
            szv[8] = fmaf(y2.x, mz, szv[8]); shv[8] = fmaf(y2.x, mh, shv[8]);
            szv[9] = fmaf(y2.y, mz, szv[9]); shv[9] = fmaf(y2.y, mh, shv[9]);
            szv[10] = fmaf(y2.z, mz, szv[10]); shv[10] = fmaf(y2.z, mh, shv[10]);
            szv[11] = fmaf(y2.w, mz, szv[11]); shv[11] = fmaf(y2.w, mh, shv[11]);
        }
        float hacc = 0.f;
        #pragma unroll
        for (int p = 0; p < 12; ++p) {
            // (1-sigmoid(sz))*tanh(sh) = u(v-1)/((1+u)(v+1)), u=e^{-sz}, v=e^{2sh}
            const float u = __expf(-szv[p]);
            const float v = __expf(2.f * shv[p]);
            const float num = u * (v - 1.f);
            const float den = fmaf(u, v, u) + (v + 1.f);
            hacc = fmaf(pr[p] * num, __builtin_amdgcn_rcpf(den), hacc);
        }
        sHA[wv][b * 33 + c] = fmaxf(hacc, 0.f);
    }

    // ---- lin1 (wave-private): 96 outputs, contiguous write h1t[n][r] ----
    {
        const int r = l;                    // 0..63
        const int bb = r / 12, p = r - bb * 12;
        float s = sl1b[p];
        #pragma unroll
        for (int cc = 0; cc < 32; ++cc) s = fmaf(sHA[wv][bb * 33 + cc], sl1w[cc * 12 + p], s);
        h1t[n * 96 + r] = s;
    }
    if (l < 32) {
        const int r = l + 64;               // 64..95
        const int bb = r / 12, p = r - bb * 12;
        float s = sl1b[p];
        #pragma unroll
        for (int cc = 0; cc < 32; ++cc) s = fmaf(sHA[wv][bb * 33 + cc], sl1w[cc * 12 + p], s);
        h1t[n * 96 + r] = s;
    }
}

// ---------------- final: out[b][t][p] += sum_{n in chunk} h1t[n][i] * W2[n][t]  (bias pre-written) ----------------
__global__ __launch_bounds__(256) void k_final(const float* __restrict__ h1t, const float* __restrict__ W2,
                                               float* __restrict__ out) {
    __shared__ float sh1[48 * FCN];   // 19.2 KB, [i][nn]
    const int tid = threadIdx.x;
    const int chunk = blockIdx.x >> 1, h = blockIdx.x & 1;
    const int n0 = chunk * FCN;
    const int i0 = h * 48;

    for (int idx = tid; idx < 48 * FCN; idx += 256) {
        const int nn = idx / 48, i = idx - nn * 48;
        sh1[i * FCN + nn] = h1t[(n0 + nn) * 96 + i0 + i];
    }
    __syncthreads();

    const int t = tid & 63, w = tid >> 6;      // 4 waves, each owns 12 i-rows
    const float* sh = &sh1[w * 12 * FCN];
    float acc[12];
    #pragma unroll
    for (int j = 0; j < 12; ++j) acc[j] = 0.f;

    for (int nn = 0; nn < FCN; nn += 4) {
        const float w20 = W2[(n0 + nn + 0) * NT + t];
        const float w21 = W2[(n0 + nn + 1) * NT + t];
        const float w22 = W2[(n0 + nn + 2) * NT + t];
        const float w23 = W2[(n0 + nn + 3) * NT + t];
        #pragma unroll
        for (int j = 0; j < 12; ++j) {
            const float4 hv = *(const float4*)&sh[j * FCN + nn];
            acc[j] = fmaf(hv.x, w20, fmaf(hv.y, w21, fmaf(hv.z, w22, fmaf(hv.w, w23, acc[j]))));
        }
    }

    float* po = out + (h * 4 + w) * 768 + t * 12;
    #pragma unroll
    for (int j = 0; j < 12; ++j) atomicAdd(po + j, acc[j]);
}

extern "C" void kernel_launch(void* const* d_in, const int* in_sizes, int n_in,
                              void* d_out, int out_size, void* d_ws, size_t ws_size,
                              hipStream_t stream) {
    const float* x    = (const float*)d_in[0];
    const int*   eidx = (const int*)d_in[1];   // int32 per harness convention
    const float* ew   = (const float*)d_in[2];
    const float* Wz   = (const float*)d_in[3];
    const float* bz   = (const float*)d_in[4];
    // d_in[5], d_in[6]: Wr, br (dead: H0 == 0)
    const float* Wh   = (const float*)d_in[7];
    const float* bh   = (const float*)d_in[8];
    const float* Lzw  = (const float*)d_in[9];
    const float* Lzb  = (const float*)d_in[10];
    // d_in[11], d_in[12]: Lr_w, Lr_b (dead)
    const float* Lhw  = (const float*)d_in[13];
    const float* Lhb  = (const float*)d_in[14];
    const float* att  = (const float*)d_in[15];
    const float* l1w  = (const float*)d_in[16];
    const float* l1b  = (const float*)d_in[17];
    const float* W2   = (const float*)d_in[18];
    const float* l2b  = (const float*)d_in[19];
    float* out = (float*)d_out;
    const int E = in_sizes[2];
    const int EB = (E + 255) / 256;

    // workspace carve-up (float offsets; all 16B-aligned)
    float* deg    = (float*)d_ws;                       // 10240 f32
    int*   count  = (int*)(deg + 10240);                // 10240 i32
    uint2* bucket = (uint2*)(count + 10240);            // NN*BCAP uint2 = 7.68 MB
    float* sm     = (float*)(bucket + NN * BCAP);       // 1024 f32
    float* h1t    = sm + 1024;                          // NN*96 f32
    unsigned short* xh = (unsigned short*)(h1t + NN * 96);   // NN*768 bf16 = 15.36 MB

    const int* rowp = eidx;        // edge_index[0]
    const int* colp = eidx + E;    // edge_index[1]

    hipMemsetAsync(d_ws, 0, 2 * 10240 * 4, stream);
    hipLaunchKernelGGL(k_xf,   dim3(XB), dim3(256), 0, stream, x, xh);
    hipLaunchKernelGGL(k_edge, dim3(EB), dim3(256), 0, stream, rowp, colp, ew, deg, count, bucket, E);
    hipLaunchKernelGGL(k_misc, dim3(2), dim3(256), 0, stream,
                       Wz, bz, Wh, bh, Lzw, Lzb, Lhw, Lhb, att, l2b, sm, out);
    hipLaunchKernelGGL(k_main, dim3(NN / 4), dim3(256), 0, stream,
                       xh, deg, count, bucket, sm, l1w, l1b, h1t);
    hipLaunchKernelGGL(k_final, dim3(FCH * 2), dim3(256), 0, stream, h1t, W2, out);
}